// Round 15
// baseline (1872.306 us; speedup 1.0000x reference)
//
#include <hip/hip_runtime.h>

// SparseCoding fused persistent kernel, fp32 VALU (R15 = R9 + occupancy only).
// Arithmetic chains bit-identical to R1/R9 (absmax must stay 4.882812e-4).
//
// Ledger: R9 (scalar W loads, 48KB LDS, (256,3), 84 VGPR AT the cap) = 1606us,
// VALUBusy 71%, 12 waves/CU. Packed-dwordx4 variants (R10/R12/R13/R14) all
// regressed; R14 isolated the step-0 peel as harmful (code-size/I-cache).
// R15 keeps R9's instruction stream VERBATIM and changes only:
//  - inp tile LDS -> 8 registers (same values; d = acc - inr unchanged).
//    LDS 48 -> 40 KB => 4 blocks/CU (was 3).
//  - __launch_bounds__(256,2): VGPR cap 128 (was 84's edge) -> ~92 live floats
//    fit with headroom, no allocator bistability, 4 waves/SIMD at <=128 VGPR.
//  => 16 waves/CU (was 12): +33% latency hiding on the same code.

#define BSZ   32768
#define DIN   128
#define DOUT  512
#define RTILE 16
#define NSTEP 10
#define NT    256
#define NBLOCKS (BSZ / RTILE)   // 2048

typedef __attribute__((ext_vector_type(2))) float f32x2;

// pack W^T fp32 into ws: Wt[i][j] = W[j][i]  (identical float values ->
// phase-2 arithmetic stays bit-identical; verified R9)
__global__ void sc_packT(const float* __restrict__ W, float* __restrict__ Wt) {
    const int tid = blockIdx.x * blockDim.x + threadIdx.x;  // 0..65535
    const int j = tid >> 7;      // 0..511
    const int i = tid & 127;     // 0..127
    Wt[i * DOUT + j] = W[j * DIN + i];
}

__global__ __launch_bounds__(NT, 2)
void sc_fused(const float* __restrict__ inp, const float* __restrict__ W,
              const float* __restrict__ Wt, float* __restrict__ out)
{
    __shared__ float x_lds[RTILE][DOUT];    // 32 KB
    __shared__ float d_lds[RTILE][DIN];     //  8 KB   (40 KB -> 4 blocks/CU)

    const int t = threadIdx.x;
    const int row0 = blockIdx.x * RTILE;

    const int i_p1 = t & 127;        // phase-1 column (0..127)
    const int rg   = (t >> 7) * 8;   // phase-1 row group (0 or 8)
    const int j0   = 2 * t;          // phase-2/update column pair (0..510)

    // Per-thread RMSProp state
    float a1[RTILE][2];
    float a2[RTILE][2];
#pragma unroll
    for (int r = 0; r < RTILE; ++r) {
        a1[r][0] = a1[r][1] = 0.f;
        a2[r][0] = a2[r][1] = 0.f;
    }

    // inp values this thread needs in phase 1 (registers; identical values)
    float inr[8];
#pragma unroll
    for (int rr = 0; rr < 8; ++rr)
        inr[rr] = inp[(row0 + rg + rr) * DIN + i_p1];

    // init x = 0
    for (int k = t; k < RTILE * DOUT; k += NT) (&x_lds[0][0])[k] = 0.f;
    __syncthreads();

    // thread-fixed base pointers (R9 verbatim)
    const float* __restrict__ wcol = W + i_p1;           // W[j][i_p1] = wcol[j*DIN]
    const float* __restrict__ wtj  = Wt + j0;            // Wt[i][j0]  = wtj[i*DOUT]

    for (int step = 0; step < NSTEP; ++step) {
        // ---- phase 1: d = x @ W - inp  (serial j-chain, identical to R1) ----
        {
            float acc[8];
#pragma unroll
            for (int rr = 0; rr < 8; ++rr) acc[rr] = 0.f;

#pragma unroll 2
            for (int j = 0; j < DOUT; j += 4) {
                const float w0 = wcol[(j + 0) * DIN];
                const float w1 = wcol[(j + 1) * DIN];
                const float w2 = wcol[(j + 2) * DIN];
                const float w3 = wcol[(j + 3) * DIN];
#pragma unroll
                for (int rr = 0; rr < 8; ++rr) {
                    const float4 xv = *(const float4*)&x_lds[rg + rr][j];  // LDS broadcast
                    acc[rr] = fmaf(xv.x, w0, acc[rr]);
                    acc[rr] = fmaf(xv.y, w1, acc[rr]);
                    acc[rr] = fmaf(xv.z, w2, acc[rr]);
                    acc[rr] = fmaf(xv.w, w3, acc[rr]);
                }
            }
#pragma unroll
            for (int rr = 0; rr < 8; ++rr)
                d_lds[rg + rr][i_p1] = acc[rr] - inr[rr];
        }
        __syncthreads();

        // ---- phase 2: gacc = d @ W^T (serial i-chain, identical to R1) ----
        {
            float acc[RTILE][2];
#pragma unroll
            for (int r = 0; r < RTILE; ++r) acc[r][0] = acc[r][1] = 0.f;

#pragma unroll 2
            for (int i = 0; i < DIN; i += 4) {
                const f32x2 wq0 = *(const f32x2*)&wtj[(i + 0) * DOUT];
                const f32x2 wq1 = *(const f32x2*)&wtj[(i + 1) * DOUT];
                const f32x2 wq2 = *(const f32x2*)&wtj[(i + 2) * DOUT];
                const f32x2 wq3 = *(const f32x2*)&wtj[(i + 3) * DOUT];
#pragma unroll
                for (int r = 0; r < RTILE; ++r) {
                    const float4 dv = *(const float4*)&d_lds[r][i];  // LDS broadcast
                    acc[r][0] = fmaf(dv.x, wq0.x, acc[r][0]);
                    acc[r][0] = fmaf(dv.y, wq1.x, acc[r][0]);
                    acc[r][0] = fmaf(dv.z, wq2.x, acc[r][0]);
                    acc[r][0] = fmaf(dv.w, wq3.x, acc[r][0]);
                    acc[r][1] = fmaf(dv.x, wq0.y, acc[r][1]);
                    acc[r][1] = fmaf(dv.y, wq1.y, acc[r][1]);
                    acc[r][1] = fmaf(dv.z, wq2.y, acc[r][1]);
                    acc[r][1] = fmaf(dv.w, wq3.y, acc[r][1]);
                }
            }

            // RMSProp + momentum update (identical to R1), x lives in LDS
#pragma unroll
            for (int r = 0; r < RTILE; ++r) {
#pragma unroll
                for (int c = 0; c < 2; ++c) {
                    const float xv  = x_lds[r][j0 + c];
                    const float g   = 2.f * acc[r][c] + 0.1f * xv * rsqrtf(xv * xv + 1e-6f);
                    const float na1 = 0.9f * a1[r][c] + 0.1f * g * g;
                    a1[r][c] = na1;
                    const float upd = 0.001f * g * rsqrtf(na1 + 1e-8f);
                    const float na2 = 0.9f * a2[r][c] - upd;
                    a2[r][c] = na2;
                    x_lds[r][j0 + c] = xv + 0.9f * na2 - upd;
                }
            }
            __syncthreads();
        }
    }

    // write final x (coalesced)
    for (int k = t; k < RTILE * DOUT; k += NT)
        out[row0 * DOUT + k] = (&x_lds[0][0])[k];
}

extern "C" void kernel_launch(void* const* d_in, const int* in_sizes, int n_in,
                              void* d_out, int out_size, void* d_ws, size_t ws_size,
                              hipStream_t stream) {
    const float* inputs = (const float*)d_in[0];
    const float* W      = (const float*)d_in[1];
    float* out          = (float*)d_out;
    float* Wt           = (float*)d_ws;   // 256 KB fp32 W^T

    sc_packT<<<dim3(256), dim3(256), 0, stream>>>(W, Wt);
    sc_fused<<<dim3(NBLOCKS), dim3(NT), 0, stream>>>(inputs, W, Wt, out);
}

// Round 16
// 1605.444 us; speedup vs baseline: 1.1662x; 1.1662x over previous
//
#include <hip/hip_runtime.h>

// SparseCoding fused persistent kernel, fp32 VALU — FINAL (R16 = R9 verbatim).
//
// R9 is the measured optimum of this session: 1606 us, absmax 4.882812e-4
// (bit-identical to the naive fp32 chain), VALUBusy 71%, zero spill.
// Six perturbations all regressed via distinct mechanisms:
//   R10 (256,4) pack        1640  (VGPR cap 64 -> scratch spill)
//   R11 (512,6) 1-col/thr   1973  (VGPR cap 40 -> 1GB scratch)
//   R12 pack+col-block      1798  (spill + L2 thrash, W re-fetch from HBM)
//   R13 512thr reg-block    2174  (rows/thread down -> W L2 traffic x3.5)
//   R14 pack+step0-peel     1787  (code-size/I-cache, VALUBusy 71->60)
//   R15 inp->regs (256,2)   1872  (occupancy unmoved; worse allocator sched)
// MFMA split-precision path (R3-R8) closed: RMSProp trajectory is chaotic
// w.r.t. ~1e-6 gradient noise; all variants plateau at 2.4-3.3e-3 vs the
// 2e-3 threshold regardless of theoretical split precision.
//
// Structure: one block owns 16 rows for all 10 steps; x in LDS, a1/a2 in
// registers; W streamed (L2-resident); phase 2 reads pre-packed fp32 W^T
// (value-identical -> bit-identical arithmetic).

#define BSZ   32768
#define DIN   128
#define DOUT  512
#define RTILE 16
#define NSTEP 10
#define NBLOCKS (BSZ / RTILE)   // 2048

typedef __attribute__((ext_vector_type(2))) float f32x2;

// pack W^T fp32 into ws: Wt[i][j] = W[j][i]
__global__ void sc_packT(const float* __restrict__ W, float* __restrict__ Wt) {
    const int tid = blockIdx.x * blockDim.x + threadIdx.x;  // 0..65535
    const int j = tid >> 7;      // 0..511 (coalesced read of W row-major)
    const int i = tid & 127;     // 0..127
    Wt[i * DOUT + j] = W[j * DIN + i];
}

__global__ __launch_bounds__(256, 3)
void sc_fused(const float* __restrict__ inp, const float* __restrict__ W,
              const float* __restrict__ Wt, float* __restrict__ out)
{
    __shared__ float x_lds[RTILE][DOUT];    // 32 KB
    __shared__ float d_lds[RTILE][DIN];     //  8 KB
    __shared__ float inp_lds[RTILE][DIN];   //  8 KB

    const int t = threadIdx.x;
    const int row0 = blockIdx.x * RTILE;

    // Per-thread RMSProp state for slots (r, j0), (r, j0+1), r = 0..15
    float a1[RTILE][2];
    float a2[RTILE][2];
#pragma unroll
    for (int r = 0; r < RTILE; ++r) {
        a1[r][0] = a1[r][1] = 0.f;
        a2[r][0] = a2[r][1] = 0.f;
    }

    // init x = 0, load inputs tile (coalesced)
    for (int k = t; k < RTILE * DOUT; k += 256) (&x_lds[0][0])[k] = 0.f;
    for (int k = t; k < RTILE * DIN;  k += 256) (&inp_lds[0][0])[k] = inp[row0 * DIN + k];
    __syncthreads();

    const int i_p1 = t & 127;        // phase-1 column (0..127)
    const int rg   = (t >> 7) * 8;   // phase-1 row group (0 or 8)
    const int j0   = 2 * t;          // phase-2/update column pair (0..510)

    // thread-fixed base pointers (helps SGPR-base + imm-offset codegen)
    const float* __restrict__ wcol = W + i_p1;           // W[j][i_p1] = wcol[j*DIN]
    const float* __restrict__ wtj  = Wt + j0;            // Wt[i][j0]  = wtj[i*DOUT]

    for (int step = 0; step < NSTEP; ++step) {
        // ---- phase 1: d = x @ W - inp  (serial j-chain, identical to R1) ----
        {
            float acc[8];
#pragma unroll
            for (int rr = 0; rr < 8; ++rr) acc[rr] = 0.f;

#pragma unroll 2
            for (int j = 0; j < DOUT; j += 4) {
                const float w0 = wcol[(j + 0) * DIN];
                const float w1 = wcol[(j + 1) * DIN];
                const float w2 = wcol[(j + 2) * DIN];
                const float w3 = wcol[(j + 3) * DIN];
#pragma unroll
                for (int rr = 0; rr < 8; ++rr) {
                    const float4 xv = *(const float4*)&x_lds[rg + rr][j];  // LDS broadcast
                    acc[rr] = fmaf(xv.x, w0, acc[rr]);
                    acc[rr] = fmaf(xv.y, w1, acc[rr]);
                    acc[rr] = fmaf(xv.z, w2, acc[rr]);
                    acc[rr] = fmaf(xv.w, w3, acc[rr]);
                }
            }
#pragma unroll
            for (int rr = 0; rr < 8; ++rr)
                d_lds[rg + rr][i_p1] = acc[rr] - inp_lds[rg + rr][i_p1];
        }
        __syncthreads();

        // ---- phase 2: gacc = d @ W^T (serial i-chain, identical to R1) ----
        {
            float acc[RTILE][2];
#pragma unroll
            for (int r = 0; r < RTILE; ++r) acc[r][0] = acc[r][1] = 0.f;

#pragma unroll 2
            for (int i = 0; i < DIN; i += 4) {
                const f32x2 wq0 = *(const f32x2*)&wtj[(i + 0) * DOUT];
                const f32x2 wq1 = *(const f32x2*)&wtj[(i + 1) * DOUT];
                const f32x2 wq2 = *(const f32x2*)&wtj[(i + 2) * DOUT];
                const f32x2 wq3 = *(const f32x2*)&wtj[(i + 3) * DOUT];
#pragma unroll
                for (int r = 0; r < RTILE; ++r) {
                    const float4 dv = *(const float4*)&d_lds[r][i];  // LDS broadcast
                    acc[r][0] = fmaf(dv.x, wq0.x, acc[r][0]);
                    acc[r][0] = fmaf(dv.y, wq1.x, acc[r][0]);
                    acc[r][0] = fmaf(dv.z, wq2.x, acc[r][0]);
                    acc[r][0] = fmaf(dv.w, wq3.x, acc[r][0]);
                    acc[r][1] = fmaf(dv.x, wq0.y, acc[r][1]);
                    acc[r][1] = fmaf(dv.y, wq1.y, acc[r][1]);
                    acc[r][1] = fmaf(dv.z, wq2.y, acc[r][1]);
                    acc[r][1] = fmaf(dv.w, wq3.y, acc[r][1]);
                }
            }

            // RMSProp + momentum update (identical to R1), x lives in LDS
#pragma unroll
            for (int r = 0; r < RTILE; ++r) {
#pragma unroll
                for (int c = 0; c < 2; ++c) {
                    const float xv  = x_lds[r][j0 + c];
                    const float g   = 2.f * acc[r][c] + 0.1f * xv * rsqrtf(xv * xv + 1e-6f);
                    const float na1 = 0.9f * a1[r][c] + 0.1f * g * g;
                    a1[r][c] = na1;
                    const float upd = 0.001f * g * rsqrtf(na1 + 1e-8f);
                    const float na2 = 0.9f * a2[r][c] - upd;
                    a2[r][c] = na2;
                    x_lds[r][j0 + c] = xv + 0.9f * na2 - upd;
                }
            }
            __syncthreads();
        }
    }

    // write final x (coalesced)
    for (int k = t; k < RTILE * DOUT; k += 256)
        out[row0 * DOUT + k] = (&x_lds[0][0])[k];
}

extern "C" void kernel_launch(void* const* d_in, const int* in_sizes, int n_in,
                              void* d_out, int out_size, void* d_ws, size_t ws_size,
                              hipStream_t stream) {
    const float* inputs = (const float*)d_in[0];
    const float* W      = (const float*)d_in[1];
    float* out          = (float*)d_out;
    float* Wt           = (float*)d_ws;   // 256 KB fp32 W^T

    sc_packT<<<dim3(256), dim3(256), 0, stream>>>(W, Wt);
    sc_fused<<<dim3(NBLOCKS), dim3(256), 0, stream>>>(inputs, W, Wt, out);
}